// Round 1
// baseline (470.687 us; speedup 1.0000x reference)
//
#include <hip/hip_runtime.h>

// ---------------------------------------------------------------------------
// JointNet: out = log_softmax( tanh(enc@W_enc+b_enc [+] pred@W_pred+b_pred) @ W_fc + b_fc )
// B=4 T=256 U=64 D=H=640 V=1024.  Output (B,T,U,V) f32 = 256 MB.
// Strategy: fp32 projections (1% of FLOPs), bf16 MFMA for the big GEMM with
// W_fc pre-swizzled into B-fragment lane order, fused log_softmax epilogue.
// ---------------------------------------------------------------------------

#define BB 4
#define TT 256
#define UU 64
#define HH 640
#define VV 1024

typedef __attribute__((ext_vector_type(8))) short bf16x8_t;   // 8 bf16 = 4 VGPRs
typedef __attribute__((ext_vector_type(4))) float f32x4_t;    // MFMA acc

__device__ __forceinline__ unsigned short f2bf(float x) {
    // round-to-nearest-even float -> bf16 bits (no NaN expected in this net)
    unsigned int u = __float_as_uint(x);
    u += 0x7fffu + ((u >> 16) & 1u);
    return (unsigned short)(u >> 16);
}

__device__ __forceinline__ float tanh_fast(float x) {
    // tanh(x) = 1 - 2/(exp(2x)+1); stable both directions (exp->inf => 1, exp->0 => -1)
    float e = __expf(2.0f * x);
    return 1.0f - 2.0f / (e + 1.0f);
}

// ---------------------------------------------------------------------------
// Kernel 1: swizzle W_fc (640x1024 f32, row-major [k][v]) into bf16 blocks in
// exact mfma_f32_16x16x32_bf16 B-fragment order:
//   block (kt, ntile): lane l, j in [0,8): element B[k=kt*32+(l>>4)*8+j][n=ntile*16+(l&15)]
//   flat index = ((kt*64 + ntile)*64 + lane)*8 + j
// => main-loop B-frag load is 16 contiguous bytes per lane.
// ---------------------------------------------------------------------------
__global__ __launch_bounds__(256) void swizzle_wfc(const float* __restrict__ Wfc,
                                                   short* __restrict__ swz) {
    const int idx  = blockIdx.x * 256 + threadIdx.x;   // 0 .. 81919 (20*64*64)
    const int lane = idx & 63;
    const int nt   = (idx >> 6) & 63;
    const int kt   = idx >> 12;                        // 0..19
    const int kb   = kt * 32 + (lane >> 4) * 8;
    const int n    = nt * 16 + (lane & 15);
    bf16x8_t v;
#pragma unroll
    for (int j = 0; j < 8; ++j)
        v[j] = (short)f2bf(Wfc[(size_t)(kb + j) * VV + n]);
    *(bf16x8_t*)(swz + (size_t)idx * 8) = v;
}

// ---------------------------------------------------------------------------
// Kernel 2: fp32 projection GEMM  C[m][h] = sum_k X[m][k]*W[k][h] + bias[h]
// X: (M,640), W: (640,640). 64x64 tile per block, 256 threads, 4x4 per thread.
// ---------------------------------------------------------------------------
__global__ __launch_bounds__(256) void proj_gemm(const float* __restrict__ X,
                                                 const float* __restrict__ W,
                                                 const float* __restrict__ bias,
                                                 float* __restrict__ C) {
    __shared__ float As[32][68];   // As[kk][row]  (A^T so compute reads are float4)
    __shared__ float Bs[32][68];   // Bs[kk][col]
    const int tid = threadIdx.x;
    const int m0  = blockIdx.x * 64;
    const int h0  = blockIdx.y * 64;
    const int tx  = tid & 15;
    const int ty  = tid >> 4;
    float accr[4][4] = {{0.f, 0.f, 0.f, 0.f}};

    for (int k0 = 0; k0 < HH; k0 += 32) {
        __syncthreads();
#pragma unroll
        for (int p = 0; p < 8; ++p) {
            int idx = p * 256 + tid;
            As[idx & 31][idx >> 5] = X[(size_t)(m0 + (idx >> 5)) * HH + k0 + (idx & 31)];
            Bs[idx >> 6][idx & 63] = W[(size_t)(k0 + (idx >> 6)) * HH + h0 + (idx & 63)];
        }
        __syncthreads();
#pragma unroll
        for (int kk = 0; kk < 32; ++kk) {
            const float4 a  = *(const float4*)&As[kk][ty * 4];
            const float4 bb = *(const float4*)&Bs[kk][tx * 4];
            accr[0][0] += a.x * bb.x; accr[0][1] += a.x * bb.y; accr[0][2] += a.x * bb.z; accr[0][3] += a.x * bb.w;
            accr[1][0] += a.y * bb.x; accr[1][1] += a.y * bb.y; accr[1][2] += a.y * bb.z; accr[1][3] += a.y * bb.w;
            accr[2][0] += a.z * bb.x; accr[2][1] += a.z * bb.y; accr[2][2] += a.z * bb.z; accr[2][3] += a.z * bb.w;
            accr[3][0] += a.w * bb.x; accr[3][1] += a.w * bb.y; accr[3][2] += a.w * bb.z; accr[3][3] += a.w * bb.w;
        }
    }
    const float4 bv = *(const float4*)&bias[h0 + tx * 4];
#pragma unroll
    for (int i = 0; i < 4; ++i) {
        float4 o;
        o.x = accr[i][0] + bv.x;
        o.y = accr[i][1] + bv.y;
        o.z = accr[i][2] + bv.z;
        o.w = accr[i][3] + bv.w;
        *(float4*)&C[(size_t)(m0 + ty * 4 + i) * HH + h0 + tx * 4] = o;
    }
}

// ---------------------------------------------------------------------------
// Kernel 3: fused joint + GEMM + log_softmax.
// One block per (b,t): 64 u-rows x 1024 vocab, K=640.
// 512 threads = 8 waves; wave w owns cols [w*128, w*128+128) = 8 n-tiles,
// 4 m-tiles of 16 rows => 32 mfma acc tiles = 128 f32 acc VGPRs/lane.
// Joint tile tanh(enc+pred) staged in LDS as bf16, K split in 2 halves of 320
// to stay under 64 KB static LDS. K-stride padded 320->328 (2-way LDS conflict
// on ds_read_b128 = free).
// ---------------------------------------------------------------------------
#define SJ 328   // jtile k-stride in ushorts (320 + 8 pad)

__global__ __launch_bounds__(512) void joint_kernel(const float* __restrict__ enc,
                                                    const float* __restrict__ pred,
                                                    const short* __restrict__ swzW,
                                                    const float* __restrict__ b_fc,
                                                    float* __restrict__ out) {
    __shared__ unsigned short jtile[64 * SJ];   // 41,984 B
    __shared__ float stats[8][64][2];           // per-wave (max, sumexp) per row
    __shared__ float logZ[64];

    const int bt   = blockIdx.x;      // b*256 + t
    const int b    = bt >> 8;
    const int tid  = threadIdx.x;
    const int wave = tid >> 6;
    const int lane = tid & 63;
    const int quad = lane >> 4;
    const int l15  = lane & 15;
    const int n0   = wave * 128;

    const float* encrow = enc + (size_t)bt * HH;
    const float* predb  = pred + (size_t)b * UU * HH;

    float bfc[8];
#pragma unroll
    for (int nt = 0; nt < 8; ++nt) bfc[nt] = b_fc[n0 + nt * 16 + l15];

    f32x4_t acc[4][8];
#pragma unroll
    for (int mt = 0; mt < 4; ++mt)
#pragma unroll
        for (int nt = 0; nt < 8; ++nt)
            acc[mt][nt] = (f32x4_t){0.f, 0.f, 0.f, 0.f};

    for (int phase = 0; phase < 2; ++phase) {
        const int kbase = phase * 320;
        __syncthreads();   // previous half's LDS reads complete
        // Fill jtile[u][k'] = bf16(tanh(enc[kbase+k'] + pred[u][kbase+k'])), k' in [0,320)
        for (int i = tid; i < 64 * 80; i += 512) {
            const int u  = i / 80;
            const int k4 = (i - u * 80) * 4;
            const float4 e = *(const float4*)(encrow + kbase + k4);
            const float4 p = *(const float4*)(predb + (size_t)u * HH + kbase + k4);
            ushort4 h;
            h.x = f2bf(tanh_fast(e.x + p.x));
            h.y = f2bf(tanh_fast(e.y + p.y));
            h.z = f2bf(tanh_fast(e.z + p.z));
            h.w = f2bf(tanh_fast(e.w + p.w));
            *(ushort4*)(jtile + u * SJ + k4) = h;
        }
        __syncthreads();

        for (int kc = 0; kc < 10; ++kc) {
            bf16x8_t af[4];
#pragma unroll
            for (int mt = 0; mt < 4; ++mt)
                af[mt] = *(const bf16x8_t*)((const short*)jtile + (mt * 16 + l15) * SJ + kc * 32 + quad * 8);
            const short* bbase = swzW + (size_t)(((phase * 10 + kc) * 64 + wave * 8) * 64 + lane) * 8;
            bf16x8_t bf[8];
#pragma unroll
            for (int nt = 0; nt < 8; ++nt)
                bf[nt] = *(const bf16x8_t*)(bbase + nt * 512);
#pragma unroll
            for (int mt = 0; mt < 4; ++mt)
#pragma unroll
                for (int nt = 0; nt < 8; ++nt)
                    acc[mt][nt] = __builtin_amdgcn_mfma_f32_16x16x32_bf16(af[mt], bf[nt], acc[mt][nt], 0, 0, 0);
        }
    }

    // ---- log_softmax epilogue ----
    // C/D layout: col = l15, row(within 16) = quad*4 + r. Lane holds, for each
    // (mt,r): row = mt*16+quad*4+r, 8 cols (one per nt) at n0+nt*16+l15.
#pragma unroll
    for (int mt = 0; mt < 4; ++mt) {
#pragma unroll
        for (int r = 0; r < 4; ++r) {
            float v[8];
            float vmax = -1e30f;
#pragma unroll
            for (int nt = 0; nt < 8; ++nt) {
                v[nt] = acc[mt][nt][r] + bfc[nt];
                vmax  = fmaxf(vmax, v[nt]);
            }
            float s = 0.f;
#pragma unroll
            for (int nt = 0; nt < 8; ++nt) s += __expf(v[nt] - vmax);
            // butterfly across the 16 lanes of this quad (same row, different cols)
#pragma unroll
            for (int off = 1; off < 16; off <<= 1) {
                const float om = __shfl_xor(vmax, off);
                const float os = __shfl_xor(s, off);
                const float nm = fmaxf(vmax, om);
                s    = s * __expf(vmax - nm) + os * __expf(om - nm);
                vmax = nm;
            }
            if (l15 == 0) {
                const int row = mt * 16 + quad * 4 + r;
                stats[wave][row][0] = vmax;
                stats[wave][row][1] = s;
            }
        }
    }
    __syncthreads();
    if (tid < 64) {
        float M = -1e30f;
#pragma unroll
        for (int w = 0; w < 8; ++w) M = fmaxf(M, stats[w][tid][0]);
        float S = 0.f;
#pragma unroll
        for (int w = 0; w < 8; ++w) S += stats[w][tid][1] * __expf(stats[w][tid][0] - M);
        logZ[tid] = M + __logf(S);
    }
    __syncthreads();

    float* orow = out + (size_t)bt * (UU * VV);
#pragma unroll
    for (int mt = 0; mt < 4; ++mt) {
#pragma unroll
        for (int r = 0; r < 4; ++r) {
            const int row = mt * 16 + quad * 4 + r;
            const float lz = logZ[row];
#pragma unroll
            for (int nt = 0; nt < 8; ++nt)
                orow[(size_t)row * VV + n0 + nt * 16 + l15] = acc[mt][nt][r] + bfc[nt] - lz;
        }
    }
}

// ---------------------------------------------------------------------------
extern "C" void kernel_launch(void* const* d_in, const int* in_sizes, int n_in,
                              void* d_out, int out_size, void* d_ws, size_t ws_size,
                              hipStream_t stream) {
    const float* enc_out  = (const float*)d_in[0];   // (4,256,640)
    const float* pred_out = (const float*)d_in[1];   // (4,64,640)
    const float* W_enc    = (const float*)d_in[2];   // (640,640)
    const float* b_enc    = (const float*)d_in[3];   // (640,)
    const float* W_pred   = (const float*)d_in[4];   // (640,640)
    const float* b_pred   = (const float*)d_in[5];   // (640,)
    const float* W_fc     = (const float*)d_in[6];   // (640,1024)
    const float* b_fc     = (const float*)d_in[7];   // (1024,)
    float* out = (float*)d_out;                      // (4,256,64,1024) f32

    char* ws = (char*)d_ws;
    // ws layout: [swzW bf16 1,310,720 B][enc f32 2,621,440 B][pred f32 655,360 B]
    short* swzW = (short*)ws;
    float* encp = (float*)(ws + 1310720);
    float* predp = (float*)(ws + 1310720 + 2621440);

    swizzle_wfc<<<320, 256, 0, stream>>>(W_fc, swzW);
    proj_gemm<<<dim3(16, 10), 256, 0, stream>>>(enc_out, W_enc, b_enc, encp);     // M=1024
    proj_gemm<<<dim3(4, 10), 256, 0, stream>>>(pred_out, W_pred, b_pred, predp);  // M=256
    joint_kernel<<<1024, 512, 0, stream>>>(encp, predp, swzW, b_fc, out);
}

// Round 2
// 431.945 us; speedup vs baseline: 1.0897x; 1.0897x over previous
//
#include <hip/hip_runtime.h>

// ---------------------------------------------------------------------------
// JointNet: out = log_softmax( tanh(enc@W_enc+b_enc [+] pred@W_pred+b_pred) @ W_fc + b_fc )
// B=4 T=256 U=64 D=H=640 V=1024.  Output (B,T,U,V) f32 = 256 MB.
// R2: persistent joint kernel (1 block/CU, 4 bt each) + LDS-only barriers so
// output stores overlap the next round's fill/MFMA; jtile stored in exact
// A-fragment order (conflict-free ds_read_b128); both projections fused in
// one launch.
// ---------------------------------------------------------------------------

#define BB 4
#define TT 256
#define UU 64
#define HH 640
#define VV 1024

typedef __attribute__((ext_vector_type(8))) short bf16x8_t;   // 8 bf16 = 4 VGPRs
typedef __attribute__((ext_vector_type(4))) float f32x4_t;    // MFMA acc

__device__ __forceinline__ unsigned short f2bf(float x) {
    unsigned int u = __float_as_uint(x);
    u += 0x7fffu + ((u >> 16) & 1u);
    return (unsigned short)(u >> 16);
}

__device__ __forceinline__ float tanh_fast(float x) {
    float e = __expf(2.0f * x);
    return 1.0f - 2.0f / (e + 1.0f);
}

// LDS-only barrier: waits DS ops (lgkmcnt) but lets global stores stay in
// flight (no vmcnt(0) drain like __syncthreads forces). Safe here: all
// cross-wave shared state (jtile/stats/logZ) is LDS; each bt's global output
// is written by exactly one block.
__device__ __forceinline__ void barrier_lds() {
    asm volatile("s_waitcnt lgkmcnt(0)\n\ts_barrier" ::: "memory");
}

// ---------------------------------------------------------------------------
// Kernel 1: swizzle W_fc (640x1024 f32) into bf16 B-fragment order:
//   flat = ((kt*64 + ntile)*64 + lane)*8 + j ;
//   element B[k=kt*32+(lane>>4)*8+j][n=ntile*16+(lane&15)]
// ---------------------------------------------------------------------------
__global__ __launch_bounds__(256) void swizzle_wfc(const float* __restrict__ Wfc,
                                                   short* __restrict__ swz) {
    const int idx  = blockIdx.x * 256 + threadIdx.x;   // 0 .. 81919
    const int lane = idx & 63;
    const int nt   = (idx >> 6) & 63;
    const int kt   = idx >> 12;
    const int kb   = kt * 32 + (lane >> 4) * 8;
    const int n    = nt * 16 + (lane & 15);
    bf16x8_t v;
#pragma unroll
    for (int j = 0; j < 8; ++j)
        v[j] = (short)f2bf(Wfc[(size_t)(kb + j) * VV + n]);
    *(bf16x8_t*)(swz + (size_t)idx * 8) = v;
}

// ---------------------------------------------------------------------------
// Kernel 2: both fp32 projections in one launch.
// blockIdx.x < 16 -> enc (M=1024); else -> pred (M=256). 64x64 tile/block.
// ---------------------------------------------------------------------------
__global__ __launch_bounds__(256) void proj_both(const float* __restrict__ enc,
                                                 const float* __restrict__ pred,
                                                 const float* __restrict__ Wenc,
                                                 const float* __restrict__ benc,
                                                 const float* __restrict__ Wpred,
                                                 const float* __restrict__ bpred,
                                                 float* __restrict__ Cenc,
                                                 float* __restrict__ Cpred) {
    __shared__ float As[32][68];
    __shared__ float Bs[32][68];
    const int bx = blockIdx.x;
    const float *X, *W, *bias;
    float* C;
    int m0;
    if (bx < 16) { X = enc;  W = Wenc;  bias = benc;  C = Cenc;  m0 = bx * 64; }
    else         { X = pred; W = Wpred; bias = bpred; C = Cpred; m0 = (bx - 16) * 64; }
    const int tid = threadIdx.x;
    const int h0  = blockIdx.y * 64;
    const int tx  = tid & 15;
    const int ty  = tid >> 4;
    float accr[4][4] = {{0.f, 0.f, 0.f, 0.f}};

    for (int k0 = 0; k0 < HH; k0 += 32) {
        __syncthreads();
#pragma unroll
        for (int p = 0; p < 8; ++p) {
            int idx = p * 256 + tid;
            As[idx & 31][idx >> 5] = X[(size_t)(m0 + (idx >> 5)) * HH + k0 + (idx & 31)];
            Bs[idx >> 6][idx & 63] = W[(size_t)(k0 + (idx >> 6)) * HH + h0 + (idx & 63)];
        }
        __syncthreads();
#pragma unroll
        for (int kk = 0; kk < 32; ++kk) {
            const float4 a  = *(const float4*)&As[kk][ty * 4];
            const float4 bb = *(const float4*)&Bs[kk][tx * 4];
            accr[0][0] += a.x * bb.x; accr[0][1] += a.x * bb.y; accr[0][2] += a.x * bb.z; accr[0][3] += a.x * bb.w;
            accr[1][0] += a.y * bb.x; accr[1][1] += a.y * bb.y; accr[1][2] += a.y * bb.z; accr[1][3] += a.y * bb.w;
            accr[2][0] += a.z * bb.x; accr[2][1] += a.z * bb.y; accr[2][2] += a.z * bb.z; accr[2][3] += a.z * bb.w;
            accr[3][0] += a.w * bb.x; accr[3][1] += a.w * bb.y; accr[3][2] += a.w * bb.z; accr[3][3] += a.w * bb.w;
        }
    }
    const float4 bv = *(const float4*)&bias[h0 + tx * 4];
#pragma unroll
    for (int i = 0; i < 4; ++i) {
        float4 o;
        o.x = accr[i][0] + bv.x;
        o.y = accr[i][1] + bv.y;
        o.z = accr[i][2] + bv.z;
        o.w = accr[i][3] + bv.w;
        *(float4*)&C[(size_t)(m0 + ty * 4 + i) * HH + h0 + tx * 4] = o;
    }
}

// ---------------------------------------------------------------------------
// Kernel 3: persistent fused joint + GEMM + log_softmax.
// Grid = 256 blocks (1/CU), 512 threads (8 waves, 2 waves/SIMD at ~232 regs);
// each block processes 4 consecutive bt values (same b -> pred L2-hot).
// Per bt: 64 u-rows x 1024 vocab, K=640 in 2 phases of 320.
// jtile is stored in A-FRAGMENT order: frag (mt,kc) at shorts
//   ((mt*10+kc)*64 + lane)*8  -> lane-contiguous ds_read_b128, conflict-free.
// Output stores of round i drain during fill/MFMA of round i+1 (barrier_lds
// does not wait vmcnt).
// ---------------------------------------------------------------------------
__global__ __launch_bounds__(512, 2) void joint_kernel(const float* __restrict__ enc,
                                                       const float* __restrict__ pred,
                                                       const short* __restrict__ swzW,
                                                       const float* __restrict__ b_fc,
                                                       float* __restrict__ out) {
    __shared__ unsigned short jtile[4 * 10 * 64 * 8];  // 40 KB, fragment order
    __shared__ float stats[8][64][2];                  // per-wave (max,sumexp)
    __shared__ float logZ[64];

    const int blk  = blockIdx.x;
    const int tid  = threadIdx.x;
    const int wave = tid >> 6;
    const int lane = tid & 63;
    const int quad = lane >> 4;
    const int l15  = lane & 15;
    const int n0   = wave * 128;

    float bfc[8];
#pragma unroll
    for (int nt = 0; nt < 8; ++nt) bfc[nt] = b_fc[n0 + nt * 16 + l15];

    for (int it = 0; it < 4; ++it) {
        const int bt = blk * 4 + it;
        const float* encrow = enc + (size_t)bt * HH;
        const float* predb  = pred + (size_t)(bt >> 8) * UU * HH;

        f32x4_t acc[4][8];
#pragma unroll
        for (int mt = 0; mt < 4; ++mt)
#pragma unroll
            for (int nt = 0; nt < 8; ++nt)
                acc[mt][nt] = (f32x4_t){0.f, 0.f, 0.f, 0.f};

        for (int phase = 0; phase < 2; ++phase) {
            const int kbase = phase * 320;
            barrier_lds();   // previous consumers of jtile/logZ done
            // Fill jtile in fragment order.
            // element (u, k'): mt=u>>4, l15'=u&15, kc=k'>>5, quad'=(k'>>3)&3, j=k'&7
            for (int i = tid; i < 64 * 80; i += 512) {
                const int u  = i / 80;
                const int k4 = (i - u * 80) * 4;          // k' of first of 4
                const float4 e = *(const float4*)(encrow + kbase + k4);
                const float4 p = *(const float4*)(predb + (size_t)u * HH + kbase + k4);
                ushort4 h;
                h.x = f2bf(tanh_fast(e.x + p.x));
                h.y = f2bf(tanh_fast(e.y + p.y));
                h.z = f2bf(tanh_fast(e.z + p.z));
                h.w = f2bf(tanh_fast(e.w + p.w));
                const int mt  = u >> 4;
                const int ul  = u & 15;
                const int kc  = k4 >> 5;
                const int qd  = (k4 >> 3) & 3;
                const int j   = k4 & 7;                   // 0 or 4
                *(ushort4*)(jtile + (((mt * 10 + kc) * 64 + qd * 16 + ul) << 3) + j) = h;
            }
            barrier_lds();   // jtile visible

            for (int kc = 0; kc < 10; ++kc) {
                bf16x8_t af[4];
#pragma unroll
                for (int mt = 0; mt < 4; ++mt)
                    af[mt] = *(const bf16x8_t*)((const short*)jtile + (((mt * 10 + kc) * 64 + lane) << 3));
                const short* bbase = swzW + (size_t)((((phase * 10 + kc) * 64 + wave * 8) * 64 + lane) << 3);
                bf16x8_t bf[8];
#pragma unroll
                for (int nt = 0; nt < 8; ++nt)
                    bf[nt] = *(const bf16x8_t*)(bbase + nt * 512);
#pragma unroll
                for (int mt = 0; mt < 4; ++mt)
#pragma unroll
                    for (int nt = 0; nt < 8; ++nt)
                        acc[mt][nt] = __builtin_amdgcn_mfma_f32_16x16x32_bf16(af[mt], bf[nt], acc[mt][nt], 0, 0, 0);
            }
        }

        // ---- log_softmax epilogue ----
        // C/D layout: col=l15, row(within 16)=quad*4+r.
#pragma unroll
        for (int mt = 0; mt < 4; ++mt) {
#pragma unroll
            for (int r = 0; r < 4; ++r) {
                float v[8];
                float vmax = -1e30f;
#pragma unroll
                for (int nt = 0; nt < 8; ++nt) {
                    v[nt] = acc[mt][nt][r] + bfc[nt];
                    vmax  = fmaxf(vmax, v[nt]);
                }
                float s = 0.f;
#pragma unroll
                for (int nt = 0; nt < 8; ++nt) s += __expf(v[nt] - vmax);
#pragma unroll
                for (int off = 1; off < 16; off <<= 1) {
                    const float om = __shfl_xor(vmax, off);
                    const float os = __shfl_xor(s, off);
                    const float nm = fmaxf(vmax, om);
                    s    = s * __expf(vmax - nm) + os * __expf(om - nm);
                    vmax = nm;
                }
                if (l15 == 0) {
                    const int row = mt * 16 + quad * 4 + r;
                    stats[wave][row][0] = vmax;
                    stats[wave][row][1] = s;
                }
            }
        }
        barrier_lds();
        if (tid < 64) {
            float M = -1e30f;
#pragma unroll
            for (int w = 0; w < 8; ++w) M = fmaxf(M, stats[w][tid][0]);
            float S = 0.f;
#pragma unroll
            for (int w = 0; w < 8; ++w) S += stats[w][tid][1] * __expf(stats[w][tid][0] - M);
            logZ[tid] = M + __logf(S);
        }
        barrier_lds();

        float* orow = out + (size_t)bt * (UU * VV);
#pragma unroll
        for (int mt = 0; mt < 4; ++mt) {
#pragma unroll
            for (int r = 0; r < 4; ++r) {
                const int row = mt * 16 + quad * 4 + r;
                const float lz = logZ[row];
#pragma unroll
                for (int nt = 0; nt < 8; ++nt)
                    orow[(size_t)row * VV + n0 + nt * 16 + l15] = acc[mt][nt][r] + bfc[nt] - lz;
            }
        }
        // stores left in flight; next iteration's barrier_lds won't drain them
    }
}

// ---------------------------------------------------------------------------
extern "C" void kernel_launch(void* const* d_in, const int* in_sizes, int n_in,
                              void* d_out, int out_size, void* d_ws, size_t ws_size,
                              hipStream_t stream) {
    const float* enc_out  = (const float*)d_in[0];   // (4,256,640)
    const float* pred_out = (const float*)d_in[1];   // (4,64,640)
    const float* W_enc    = (const float*)d_in[2];   // (640,640)
    const float* b_enc    = (const float*)d_in[3];   // (640,)
    const float* W_pred   = (const float*)d_in[4];   // (640,640)
    const float* b_pred   = (const float*)d_in[5];   // (640,)
    const float* W_fc     = (const float*)d_in[6];   // (640,1024)
    const float* b_fc     = (const float*)d_in[7];   // (1024,)
    float* out = (float*)d_out;                      // (4,256,64,1024) f32

    char* ws = (char*)d_ws;
    short* swzW  = (short*)ws;                       // 1,310,720 B
    float* encp  = (float*)(ws + 1310720);           // 2,621,440 B
    float* predp = (float*)(ws + 1310720 + 2621440); // 655,360 B

    swizzle_wfc<<<320, 256, 0, stream>>>(W_fc, swzW);
    proj_both<<<dim3(20, 10), 256, 0, stream>>>(enc_out, pred_out,
                                                W_enc, b_enc, W_pred, b_pred,
                                                encp, predp);
    joint_kernel<<<256, 512, 0, stream>>>(encp, predp, swzW, b_fc, out);
}